// Round 5
// baseline (152.453 us; speedup 1.0000x reference)
//
#include <hip/hip_runtime.h>
#include <math.h>

// Capsule conv + dynamic routing via fp16 MFMA (16x16x32).
// Precision: A single fp16 (RNE), B split fp16 hi+lo -> acc += A*Bh + A*Bl.
// (R1 calibration: A-single-bf16 gave 2.15e-2; fp16 is 4x finer -> ~6e-3 expected.)
//
// x:    [B=32][H=32][W=32][128]  fp32 (128 = i*16+cin)
// wts:  [i=8][tap=9][cin=16][o=128] fp32 -> prep to lane-ordered fp16:
//       w[(i*5+q)][c][lane=quad*16+fi][j]  (k = q*32+quad*8+j, zero for k>=144)
// out:  [B][H][W][128] fp32 (o = c*16+f)
//
// Main: grid=1024 (b*32+h), block=1024 = 16 waves = (Mt 0..1) x (c 0..7).
// MFMA tile M=16 px, N=16 f, K=160. C/D: f=lane&15, px = Mt*16 + (lane>>4)*4 + reg.
// Logits live only in LDS; f-reductions via DPP row_ror; softmax-over-c via
// padded LDS (stride 76/9 -> <=2-way, free).

typedef _Float16 fp16x8 __attribute__((ext_vector_type(8)));
typedef float f32x4 __attribute__((ext_vector_type(4)));

#define EPS 1e-7f
constexpr int PSTRIDE = 136;   // fp16 elems; 272B row stride (17*16B) keeps 16B alignment
constexpr int LSTRIDE = 76;    // dwords per pixel in lg/r arrays (76 % 32 = 12)
constexpr int W_ELEMS = 40 * 8 * 64 * 8;   // 163840 per (hi|lo)

template<int CTRL>
__device__ __forceinline__ float dpp_rot(float v) {
    int s = __float_as_int(v);
    return __int_as_float(__builtin_amdgcn_update_dpp(s, s, CTRL, 0xF, 0xF, false));
}
// sum over the 16-lane row (all lanes get the same total)
__device__ __forceinline__ float sum16(float v) {
    v += dpp_rot<0x128>(v);   // row_ror:8
    v += dpp_rot<0x124>(v);   // row_ror:4
    v += dpp_rot<0x122>(v);   // row_ror:2
    v += dpp_rot<0x121>(v);   // row_ror:1
    return v;
}

// prep: 64 blocks = (i 0..7) x (ch 0..1, o-half) x (part 0..3).
// Coalesced fp32 reads -> LDS slab -> scattered LDS reads -> coalesced fp16 stores.
__global__ __launch_bounds__(256)
void prep_weights(const float* __restrict__ wts,
                  _Float16* __restrict__ w_hi,
                  _Float16* __restrict__ w_lo) {
    __shared__ float s[144 * 64];              // 36.9 KB: rows k=tap*16+cin, cols o-half
    const int bid  = blockIdx.x;
    const int i    = bid >> 3;
    const int ch   = (bid >> 2) & 1;
    const int part = bid & 3;

    const float4* src4 = (const float4*)wts;
    float4* s4 = (float4*)s;
    for (int t = threadIdx.x; t < 2304; t += 256) {      // 144 rows x 16 float4
        int r = t >> 4, c4 = t & 15;
        s4[t] = src4[i * 4608 + r * 32 + ch * 16 + c4];
    }
    __syncthreads();

    for (int t = threadIdx.x; t < 2560; t += 256) {
        int d  = part * 2560 + t;            // within (i,ch): ((q*4+cl)*64+lane)*8+j
        int q  = d >> 11;
        int cl = (d >> 9) & 3;
        int ln = (d >> 3) & 63;
        int j  = d & 7;
        int quad = ln >> 4, fi = ln & 15;
        int k = q * 32 + quad * 8 + j;
        float w = (k < 144) ? s[k * 64 + cl * 16 + fi] : 0.f;
        _Float16 hi = (_Float16)w;                       // RNE
        _Float16 lo = (_Float16)(w - (float)hi);
        int dst = ((i * 5 + q) * 8 + ch * 4 + cl) * 512 + ln * 8 + j;
        w_hi[dst] = hi;
        w_lo[dst] = lo;
    }
}

__global__ __launch_bounds__(1024, 4)
void capsule_mfma_kernel(const float* __restrict__ x,
                         const _Float16* __restrict__ w_hi,
                         const _Float16* __restrict__ w_lo,
                         const float* __restrict__ bias,
                         float* __restrict__ out)
{
    __shared__ _Float16 patch[3 * 34 * PSTRIDE];        // 27744 B
    __shared__ float lg_arr[32 * LSTRIDE];              // [px*76 + i*9 + c]
    __shared__ float r_arr[32 * LSTRIDE];               // [px*76 + c*9 + i]

    const int tid  = threadIdx.x;
    const int lane = tid & 63;
    const int wv   = tid >> 6;
    const int c    = wv & 7;
    const int Mt   = wv >> 3;
    const int fi   = lane & 15;
    const int quad = lane >> 4;

    const int bid = blockIdx.x;
    const int h = bid & 31, b = bid >> 5;

    // ---- stage input patch rows h-1..h+1, cols -1..32, fp16 ----
    const float4* x4 = (const float4*)x;
    for (int idx = tid; idx < 102 * 32; idx += 1024) {
        int ch4  = idx & 31;
        int slot = idx >> 5;
        int row  = slot / 34;
        int colp = slot - row * 34;
        int gh = h - 1 + row;
        int gw = colp - 1;
        float4 v = {0.f, 0.f, 0.f, 0.f};
        if ((unsigned)gh < 32u && (unsigned)gw < 32u)
            v = x4[(((b * 32 + gh) * 32 + gw) << 5) + ch4];
        _Float16 ph[4];
        ph[0] = (_Float16)v.x; ph[1] = (_Float16)v.y;
        ph[2] = (_Float16)v.z; ph[3] = (_Float16)v.w;
        *(ushort4*)&patch[slot * PSTRIDE + ch4 * 4] = *(const ushort4*)ph;
    }
    __syncthreads();

    // ---- per-lane A offsets (k = q*32 + quad*8 + j; tap = 2q + (quad>>1)) ----
    int a_off[5];
    #pragma unroll
    for (int q = 0; q < 5; ++q) {
        int tap = 2 * q + (quad >> 1);
        if (tap > 8) tap = 8;                 // pad region: B is zero there
        int dy = tap / 3, dx = tap - dy * 3;
        a_off[q] = (dy * 34 + (Mt * 16 + fi + dx)) * PSTRIDE + (quad & 1) * 8;
    }

    // ---- conv via MFMA ----
    f32x4 acc[8];
    #pragma unroll
    for (int i = 0; i < 8; ++i) acc[i] = (f32x4){0.f, 0.f, 0.f, 0.f};

    const int lane8 = lane * 8;
    #pragma unroll
    for (int q = 0; q < 5; ++q) {
        #pragma unroll
        for (int i = 0; i < 8; ++i) {
            int boff = ((i * 5 + q) * 8 + c) * 512 + lane8;
            fp16x8 bh = *(const fp16x8*)(w_hi + boff);
            fp16x8 bl = *(const fp16x8*)(w_lo + boff);
            fp16x8 ah = *(const fp16x8*)(patch + a_off[q] + i * 16);
            acc[i] = __builtin_amdgcn_mfma_f32_16x16x32_f16(ah, bh, acc[i], 0, 0, 0);
            acc[i] = __builtin_amdgcn_mfma_f32_16x16x32_f16(ah, bl, acc[i], 0, 0, 0);
        }
    }

    // ---- dynamic routing ----
    const float bb  = bias[c * 16 + fi];
    const int   px0 = Mt * 16 + quad * 4;
    float act[4];

    // iter 0: route = 1/8 uniform
    #pragma unroll
    for (int r = 0; r < 4; ++r) {
        float s = 0.f;
        #pragma unroll
        for (int i = 0; i < 8; ++i) s += acc[i][r];
        float pre = s * 0.125f + bb;
        float s2 = sum16(pre * pre);
        float scale = s2 * __builtin_amdgcn_rsqf(s2 + EPS) * __builtin_amdgcn_rcpf(1.f + s2);
        act[r] = scale * pre;
    }
    #pragma unroll
    for (int i = 0; i < 8; ++i)
        #pragma unroll
        for (int r = 0; r < 4; ++r) {
            float a = sum16(acc[i][r] * act[r]);
            if (fi == 0) lg_arr[(px0 + r) * LSTRIDE + i * 9 + c] = a;
        }
    __syncthreads();
    if (tid < 256) {   // softmax over c for each (px, i)
        int p = tid >> 3, ii = tid & 7;
        const float* lrow = &lg_arr[p * LSTRIDE + ii * 9];
        float m = lrow[0];
        #pragma unroll
        for (int cc = 1; cc < 8; ++cc) m = fmaxf(m, lrow[cc]);
        float e[8]; float den = 0.f;
        #pragma unroll
        for (int cc = 0; cc < 8; ++cc) { e[cc] = __expf(lrow[cc] - m); den += e[cc]; }
        float rd = __builtin_amdgcn_rcpf(den);
        #pragma unroll
        for (int cc = 0; cc < 8; ++cc) r_arr[p * LSTRIDE + cc * 9 + ii] = e[cc] * rd;
    }
    __syncthreads();

    // iter 1
    #pragma unroll
    for (int r = 0; r < 4; ++r) {
        const float* rr = &r_arr[(px0 + r) * LSTRIDE + c * 9];
        float s = 0.f;
        #pragma unroll
        for (int i = 0; i < 8; ++i) s = fmaf(rr[i], acc[i][r], s);
        float pre = s + bb;
        float s2 = sum16(pre * pre);
        float scale = s2 * __builtin_amdgcn_rsqf(s2 + EPS) * __builtin_amdgcn_rcpf(1.f + s2);
        act[r] = scale * pre;
    }
    #pragma unroll
    for (int i = 0; i < 8; ++i)
        #pragma unroll
        for (int r = 0; r < 4; ++r) {
            float a = sum16(acc[i][r] * act[r]);
            if (fi == 0) lg_arr[(px0 + r) * LSTRIDE + i * 9 + c] += a;
        }
    __syncthreads();
    if (tid < 256) {
        int p = tid >> 3, ii = tid & 7;
        const float* lrow = &lg_arr[p * LSTRIDE + ii * 9];
        float m = lrow[0];
        #pragma unroll
        for (int cc = 1; cc < 8; ++cc) m = fmaxf(m, lrow[cc]);
        float e[8]; float den = 0.f;
        #pragma unroll
        for (int cc = 0; cc < 8; ++cc) { e[cc] = __expf(lrow[cc] - m); den += e[cc]; }
        float rd = __builtin_amdgcn_rcpf(den);
        #pragma unroll
        for (int cc = 0; cc < 8; ++cc) r_arr[p * LSTRIDE + cc * 9 + ii] = e[cc] * rd;
    }
    __syncthreads();

    // iter 2: final activation -> out
    #pragma unroll
    for (int r = 0; r < 4; ++r) {
        const float* rr = &r_arr[(px0 + r) * LSTRIDE + c * 9];
        float s = 0.f;
        #pragma unroll
        for (int i = 0; i < 8; ++i) s = fmaf(rr[i], acc[i][r], s);
        float pre = s + bb;
        float s2 = sum16(pre * pre);
        float scale = s2 * __builtin_amdgcn_rsqf(s2 + EPS) * __builtin_amdgcn_rcpf(1.f + s2);
        int px = px0 + r;
        out[(((b * 32 + h) * 32 + px) << 7) + c * 16 + fi] = scale * pre;
    }
}

extern "C" void kernel_launch(void* const* d_in, const int* in_sizes, int n_in,
                              void* d_out, int out_size, void* d_ws, size_t ws_size,
                              hipStream_t stream) {
    const float* x    = (const float*)d_in[0];
    const float* wts  = (const float*)d_in[1];
    const float* bias = (const float*)d_in[2];
    float* out        = (float*)d_out;

    _Float16* w_hi = (_Float16*)d_ws;
    _Float16* w_lo = w_hi + W_ELEMS;

    prep_weights<<<dim3(64), dim3(256), 0, stream>>>(wts, w_hi, w_lo);
    capsule_mfma_kernel<<<dim3(1024), dim3(1024), 0, stream>>>(x, w_hi, w_lo, bias, out);
}

// Round 6
// 121.246 us; speedup vs baseline: 1.2574x; 1.2574x over previous
//
#include <hip/hip_runtime.h>
#include <math.h>

// Capsule conv + dynamic routing via fp16 MFMA (16x16x32).
// Precision: A single fp16 (RNE), B single fp16 (RNE). Calibration: R5 (A-fp16,
// B-split) measured absmax 3.9e-3 (= output-quantization floor); dropping B-lo
// adds ~3e-3 worst case -> ~6-9e-3 vs threshold 1.81e-2.
//
// x:    [B=32][H=32][W=32][128]  fp32 (128 = i*16+cin)
// wts:  [i=8][tap=9][cin=16][o=128] fp32 -> prep to lane-ordered fp16:
//       w[(i*5+q)][c][lane=quad*16+fi][j]  (k = q*32+quad*8+j, zero for k>=144)
// out:  [B][H][W][128] fp32 (o = c*16+f)
//
// Main: grid=1024 (b*32+h), block=1024 = 16 waves = (Mt 0..1) x (c 0..7).
// MFMA tile M=16 px, N=16 f, K=160. C/D: f=lane&15, px = Mt*16 + (lane>>4)*4 + reg.
// OCCUPANCY IS ON THE 64-REG CLIFF: acc = 32 AGPRs; launch_bounds(1024,8) forces
// total VGPR+AGPR <= 64 so 2 blocks (32 waves) stay resident per CU. R5 regressed
// 83->92us because 36+32=68 regs silently dropped residency to 1 block.

typedef _Float16 fp16x8 __attribute__((ext_vector_type(8)));
typedef float f32x4 __attribute__((ext_vector_type(4)));

#define EPS 1e-7f
constexpr int PSTRIDE = 136;   // fp16 elems; 272B row stride: 16B-aligned, 2-way banks (free)
constexpr int LSTRIDE = 76;    // dwords per pixel in lg/r arrays (76 % 32 = 12)
constexpr int W_ELEMS = 40 * 8 * 64 * 8;   // 163840

template<int CTRL>
__device__ __forceinline__ float dpp_rot(float v) {
    int s = __float_as_int(v);
    return __int_as_float(__builtin_amdgcn_update_dpp(s, s, CTRL, 0xF, 0xF, false));
}
// sum over the 16-lane row (all lanes get the same total)
__device__ __forceinline__ float sum16(float v) {
    v += dpp_rot<0x128>(v);   // row_ror:8
    v += dpp_rot<0x124>(v);   // row_ror:4
    v += dpp_rot<0x122>(v);   // row_ror:2
    v += dpp_rot<0x121>(v);   // row_ror:1
    return v;
}

// prep: 64 blocks = (i 0..7) x (ch 0..1, o-half) x (part 0..3).
// Coalesced fp32 reads -> LDS slab -> scattered LDS reads -> coalesced fp16 stores.
__global__ __launch_bounds__(256)
void prep_weights(const float* __restrict__ wts,
                  _Float16* __restrict__ w_hi) {
    __shared__ float s[144 * 64];              // 36.9 KB: rows k=tap*16+cin, cols o-half
    const int bid  = blockIdx.x;
    const int i    = bid >> 3;
    const int ch   = (bid >> 2) & 1;
    const int part = bid & 3;

    const float4* src4 = (const float4*)wts;
    float4* s4 = (float4*)s;
    for (int t = threadIdx.x; t < 2304; t += 256) {      // 144 rows x 16 float4
        int r = t >> 4, c4 = t & 15;
        s4[t] = src4[i * 4608 + r * 32 + ch * 16 + c4];
    }
    __syncthreads();

    for (int t = threadIdx.x; t < 2560; t += 256) {
        int d  = part * 2560 + t;            // within (i,ch): ((q*4+cl)*64+lane)*8+j
        int q  = d >> 11;
        int cl = (d >> 9) & 3;
        int ln = (d >> 3) & 63;
        int j  = d & 7;
        int quad = ln >> 4, fi = ln & 15;
        int k = q * 32 + quad * 8 + j;
        float w = (k < 144) ? s[k * 64 + cl * 16 + fi] : 0.f;
        int dst = ((i * 5 + q) * 8 + ch * 4 + cl) * 512 + ln * 8 + j;
        w_hi[dst] = (_Float16)w;             // RNE
    }
}

__global__ __launch_bounds__(1024, 8)
void capsule_mfma_kernel(const float* __restrict__ x,
                         const _Float16* __restrict__ w_hi,
                         const float* __restrict__ bias,
                         float* __restrict__ out)
{
    __shared__ _Float16 patch[3 * 34 * PSTRIDE];        // 27744 B
    __shared__ float lg_arr[32 * LSTRIDE];              // [px*76 + i*9 + c]
    __shared__ float r_arr[32 * LSTRIDE];               // [px*76 + c*9 + i]

    const int tid  = threadIdx.x;
    const int lane = tid & 63;
    const int wv   = tid >> 6;
    const int c    = wv & 7;
    const int Mt   = wv >> 3;
    const int fi   = lane & 15;
    const int quad = lane >> 4;

    const int bid = blockIdx.x;
    const int h = bid & 31, b = bid >> 5;

    // ---- stage input patch rows h-1..h+1, cols -1..32, fp16 ----
    const float4* x4 = (const float4*)x;
    for (int idx = tid; idx < 102 * 32; idx += 1024) {
        int ch4  = idx & 31;
        int slot = idx >> 5;
        int row  = slot / 34;
        int colp = slot - row * 34;
        int gh = h - 1 + row;
        int gw = colp - 1;
        float4 v = {0.f, 0.f, 0.f, 0.f};
        if ((unsigned)gh < 32u && (unsigned)gw < 32u)
            v = x4[(((b * 32 + gh) * 32 + gw) << 5) + ch4];
        _Float16 ph[4];
        ph[0] = (_Float16)v.x; ph[1] = (_Float16)v.y;
        ph[2] = (_Float16)v.z; ph[3] = (_Float16)v.w;
        *(ushort4*)&patch[slot * PSTRIDE + ch4 * 4] = *(const ushort4*)ph;
    }
    __syncthreads();

    // ---- per-lane A offsets (k = q*32 + quad*8 + j; tap = 2q + (quad>>1)) ----
    int a_off[5];
    #pragma unroll
    for (int q = 0; q < 5; ++q) {
        int tap = 2 * q + (quad >> 1);
        if (tap > 8) tap = 8;                 // pad region: B is zero there
        int dy = tap / 3, dx = tap - dy * 3;
        a_off[q] = (dy * 34 + (Mt * 16 + fi + dx)) * PSTRIDE + (quad & 1) * 8;
    }

    // ---- conv via MFMA: 40 steps of (1 B-load from L2, 1 A ds_read, 1 MFMA) ----
    f32x4 acc[8];
    #pragma unroll
    for (int i = 0; i < 8; ++i) acc[i] = (f32x4){0.f, 0.f, 0.f, 0.f};

    const int lane8 = lane * 8;
    #pragma unroll
    for (int q = 0; q < 5; ++q) {
        #pragma unroll
        for (int i = 0; i < 8; ++i) {
            int boff = ((i * 5 + q) * 8 + c) * 512 + lane8;
            fp16x8 bh = *(const fp16x8*)(w_hi + boff);
            fp16x8 ah = *(const fp16x8*)(patch + a_off[q] + i * 16);
            acc[i] = __builtin_amdgcn_mfma_f32_16x16x32_f16(ah, bh, acc[i], 0, 0, 0);
        }
    }

    // ---- dynamic routing ----
    const float bb  = bias[c * 16 + fi];
    const int   px0 = Mt * 16 + quad * 4;
    float act[4];

    // iter 0: route = 1/8 uniform
    #pragma unroll
    for (int r = 0; r < 4; ++r) {
        float s = 0.f;
        #pragma unroll
        for (int i = 0; i < 8; ++i) s += acc[i][r];
        float pre = s * 0.125f + bb;
        float s2 = sum16(pre * pre);
        float scale = s2 * __builtin_amdgcn_rsqf(s2 + EPS) * __builtin_amdgcn_rcpf(1.f + s2);
        act[r] = scale * pre;
    }
    #pragma unroll
    for (int i = 0; i < 8; ++i)
        #pragma unroll
        for (int r = 0; r < 4; ++r) {
            float a = sum16(acc[i][r] * act[r]);
            if (fi == 0) lg_arr[(px0 + r) * LSTRIDE + i * 9 + c] = a;
        }
    __syncthreads();
    if (tid < 256) {   // softmax over c for each (px, i)
        int p = tid >> 3, ii = tid & 7;
        const float* lrow = &lg_arr[p * LSTRIDE + ii * 9];
        float m = lrow[0];
        #pragma unroll
        for (int cc = 1; cc < 8; ++cc) m = fmaxf(m, lrow[cc]);
        float e[8]; float den = 0.f;
        #pragma unroll
        for (int cc = 0; cc < 8; ++cc) { e[cc] = __expf(lrow[cc] - m); den += e[cc]; }
        float rd = __builtin_amdgcn_rcpf(den);
        #pragma unroll
        for (int cc = 0; cc < 8; ++cc) r_arr[p * LSTRIDE + cc * 9 + ii] = e[cc] * rd;
    }
    __syncthreads();

    // iter 1
    #pragma unroll
    for (int r = 0; r < 4; ++r) {
        const float* rr = &r_arr[(px0 + r) * LSTRIDE + c * 9];
        float s = 0.f;
        #pragma unroll
        for (int i = 0; i < 8; ++i) s = fmaf(rr[i], acc[i][r], s);
        float pre = s + bb;
        float s2 = sum16(pre * pre);
        float scale = s2 * __builtin_amdgcn_rsqf(s2 + EPS) * __builtin_amdgcn_rcpf(1.f + s2);
        act[r] = scale * pre;
    }
    #pragma unroll
    for (int i = 0; i < 8; ++i)
        #pragma unroll
        for (int r = 0; r < 4; ++r) {
            float a = sum16(acc[i][r] * act[r]);
            if (fi == 0) lg_arr[(px0 + r) * LSTRIDE + i * 9 + c] += a;
        }
    __syncthreads();
    if (tid < 256) {
        int p = tid >> 3, ii = tid & 7;
        const float* lrow = &lg_arr[p * LSTRIDE + ii * 9];
        float m = lrow[0];
        #pragma unroll
        for (int cc = 1; cc < 8; ++cc) m = fmaxf(m, lrow[cc]);
        float e[8]; float den = 0.f;
        #pragma unroll
        for (int cc = 0; cc < 8; ++cc) { e[cc] = __expf(lrow[cc] - m); den += e[cc]; }
        float rd = __builtin_amdgcn_rcpf(den);
        #pragma unroll
        for (int cc = 0; cc < 8; ++cc) r_arr[p * LSTRIDE + cc * 9 + ii] = e[cc] * rd;
    }
    __syncthreads();

    // iter 2: final activation -> out
    #pragma unroll
    for (int r = 0; r < 4; ++r) {
        const float* rr = &r_arr[(px0 + r) * LSTRIDE + c * 9];
        float s = 0.f;
        #pragma unroll
        for (int i = 0; i < 8; ++i) s = fmaf(rr[i], acc[i][r], s);
        float pre = s + bb;
        float s2 = sum16(pre * pre);
        float scale = s2 * __builtin_amdgcn_rsqf(s2 + EPS) * __builtin_amdgcn_rcpf(1.f + s2);
        int px = px0 + r;
        out[(((b * 32 + h) * 32 + px) << 7) + c * 16 + fi] = scale * pre;
    }
}

extern "C" void kernel_launch(void* const* d_in, const int* in_sizes, int n_in,
                              void* d_out, int out_size, void* d_ws, size_t ws_size,
                              hipStream_t stream) {
    const float* x    = (const float*)d_in[0];
    const float* wts  = (const float*)d_in[1];
    const float* bias = (const float*)d_in[2];
    float* out        = (float*)d_out;

    _Float16* w_hi = (_Float16*)d_ws;

    prep_weights<<<dim3(64), dim3(256), 0, stream>>>(wts, w_hi);
    capsule_mfma_kernel<<<dim3(1024), dim3(1024), 0, stream>>>(x, w_hi, bias, out);
}

// Round 8
// 118.245 us; speedup vs baseline: 1.2893x; 1.0254x over previous
//
#include <hip/hip_runtime.h>
#include <math.h>

// Capsule conv + dynamic routing via fp16 MFMA (16x16x32).
// Two dispatches: prep (fp32 weights -> lane-ordered fp16, direct scatter, 640
// blocks) then fused conv+routing. NOTE: hipLaunchCooperativeKernel is NOT
// graph-capturable in this harness (R7 failed with poison passthrough) — do not
// retry grid-sync fusion.
//
// Precision: A single fp16 (RNE), B single fp16 (RNE). Measured absmax 4.9e-3
// vs threshold 1.81e-2 (R6).
//
// x:    [B=32][H=32][W=32][128] fp32 (128 = i*16+cin)
// wts:  [i=8][tap=9][cin=16][o=128] fp32 -> w16[(i*5+q)][c][lane=quad*16+fi][j]
//       (k = q*32+quad*8+j, zero for k>=144)
// out:  [B][H][W][128] fp32 (o = c*16+f)
//
// Main: grid=1024 (b*32+h), block=1024 = 16 waves = (Mt 0..1) x (c 0..7).
// MFMA tile M=16 px, N=16 f, K=160. C/D: f=lane&15, px = Mt*16 + (lane>>4)*4 + reg.
// OCCUPANCY CLIFF: acc = 32 AGPRs (unified file); launch_bounds(1024,8) forces
// VGPR+AGPR <= 64 so 2 blocks (32 waves) stay resident/CU. R5 regressed at 68 regs.

typedef _Float16 fp16x8 __attribute__((ext_vector_type(8)));
typedef float f32x4 __attribute__((ext_vector_type(4)));

#define EPS 1e-7f
constexpr int PSTRIDE = 136;   // fp16 elems; 272B row stride: 16B-aligned, 2-way banks (free)
constexpr int LSTRIDE = 76;    // lg_arr: dwords per pixel ([px*76 + i*9 + c])
constexpr int PXS     = 76;    // r_arr: dwords per pixel ([px*76 + c*8 + i]);
                               // quad stride 304B -> 2-way (free); 16B-aligned float4 reads
constexpr int W_ELEMS = 40 * 8 * 64 * 8;   // 163840

template<int CTRL>
__device__ __forceinline__ float dpp_rot(float v) {
    int s = __float_as_int(v);
    return __int_as_float(__builtin_amdgcn_update_dpp(s, s, CTRL, 0xF, 0xF, false));
}
// sum over the 16-lane row (all lanes get the same total)
__device__ __forceinline__ float sum16(float v) {
    v += dpp_rot<0x128>(v);   // row_ror:8
    v += dpp_rot<0x124>(v);   // row_ror:4
    v += dpp_rot<0x122>(v);   // row_ror:2
    v += dpp_rot<0x121>(v);   // row_ror:1
    return v;
}

// prep: direct scatter, 640 blocks x 256 threads, 1 element each.
// Coalesced fp16 stores; scattered fp32 reads (512B stride) stay in L2, ~10 MB.
__global__ __launch_bounds__(256)
void prep_weights(const float* __restrict__ wts,
                  _Float16* __restrict__ w16) {
    int n = blockIdx.x * 256 + threadIdx.x;        // 0..163839
    if (n >= W_ELEMS) return;
    int j    = n & 7;
    int ln   = (n >> 3) & 63;
    int c0   = (n >> 9) & 7;
    int iq   = n >> 12;                            // i*5+q
    int i0   = iq / 5;
    int q0   = iq - i0 * 5;
    int quad0 = ln >> 4, fi0 = ln & 15;
    int k = q0 * 32 + quad0 * 8 + j;
    float w = 0.f;
    if (k < 144) w = wts[(i0 * 144 + k) * 128 + c0 * 16 + fi0];
    w16[n] = (_Float16)w;                          // RNE
}

__global__ __launch_bounds__(1024, 8)
void capsule_mfma_kernel(const float* __restrict__ x,
                         const _Float16* __restrict__ w16,
                         const float* __restrict__ bias,
                         float* __restrict__ out)
{
    __shared__ _Float16 patch[3 * 34 * PSTRIDE];        // 27744 B
    __shared__ float lg_arr[32 * LSTRIDE];              // 9728 B
    __shared__ float r_arr[32 * PXS];                   // 9728 B

    const int tid  = threadIdx.x;
    const int lane = tid & 63;
    const int wv   = tid >> 6;
    const int c    = wv & 7;
    const int Mt   = wv >> 3;
    const int fi   = lane & 15;
    const int quad = lane >> 4;
    const int lane8 = lane * 8;

    const int bid = blockIdx.x;
    const int h = bid & 31, b = bid >> 5;

    // ---- stage input patch rows h-1..h+1, cols -1..32, fp16 ----
    const float4* x4 = (const float4*)x;
    for (int idx = tid; idx < 102 * 32; idx += 1024) {
        int ch4  = idx & 31;
        int slot = idx >> 5;
        int row  = slot / 34;
        int colp = slot - row * 34;
        int gh = h - 1 + row;
        int gw = colp - 1;
        float4 v = {0.f, 0.f, 0.f, 0.f};
        if ((unsigned)gh < 32u && (unsigned)gw < 32u)
            v = x4[(((b * 32 + gh) * 32 + gw) << 5) + ch4];
        _Float16 ph[4];
        ph[0] = (_Float16)v.x; ph[1] = (_Float16)v.y;
        ph[2] = (_Float16)v.z; ph[3] = (_Float16)v.w;
        *(ushort4*)&patch[slot * PSTRIDE + ch4 * 4] = *(const ushort4*)ph;
    }
    __syncthreads();

    // ---- per-lane A offsets (k = q*32 + quad*8 + j; tap = 2q + (quad>>1)) ----
    int a_off[5];
    #pragma unroll
    for (int q = 0; q < 5; ++q) {
        int tap = 2 * q + (quad >> 1);
        if (tap > 8) tap = 8;                 // pad region: B is zero there
        int dy = tap / 3, dx = tap - dy * 3;
        a_off[q] = (dy * 34 + (Mt * 16 + fi + dx)) * PSTRIDE + (quad & 1) * 8;
    }

    // ---- conv via MFMA: 40 steps of (1 B-load from L2, 1 A ds_read, 1 MFMA) ----
    f32x4 acc[8];
    #pragma unroll
    for (int i = 0; i < 8; ++i) acc[i] = (f32x4){0.f, 0.f, 0.f, 0.f};

    #pragma unroll
    for (int q = 0; q < 5; ++q) {
        #pragma unroll
        for (int i = 0; i < 8; ++i) {
            int boff = ((i * 5 + q) * 8 + c) * 512 + lane8;
            fp16x8 bh = *(const fp16x8*)(w16 + boff);
            fp16x8 ah = *(const fp16x8*)(patch + a_off[q] + i * 16);
            acc[i] = __builtin_amdgcn_mfma_f32_16x16x32_f16(ah, bh, acc[i], 0, 0, 0);
        }
    }

    // ---- dynamic routing ----
    const float bb  = bias[c * 16 + fi];
    const int   px0 = Mt * 16 + quad * 4;
    float act[4];

    // iter 0: route = 1/8 uniform
    #pragma unroll
    for (int r = 0; r < 4; ++r) {
        float s = 0.f;
        #pragma unroll
        for (int i = 0; i < 8; ++i) s += acc[i][r];
        float pre = s * 0.125f + bb;
        float s2 = sum16(pre * pre);
        float scale = s2 * __builtin_amdgcn_rsqf(s2 + EPS) * __builtin_amdgcn_rcpf(1.f + s2);
        act[r] = scale * pre;
    }
    #pragma unroll
    for (int i = 0; i < 8; ++i)
        #pragma unroll
        for (int r = 0; r < 4; ++r) {
            float a = sum16(acc[i][r] * act[r]);
            if (fi == 0) lg_arr[(px0 + r) * LSTRIDE + i * 9 + c] = a;
        }
    __syncthreads();
    if (tid < 256) {   // softmax over c for each (px, i)
        int p = tid >> 3, ii = tid & 7;
        const float* lrow = &lg_arr[p * LSTRIDE + ii * 9];
        float m = lrow[0];
        #pragma unroll
        for (int cc = 1; cc < 8; ++cc) m = fmaxf(m, lrow[cc]);
        float e[8]; float den = 0.f;
        #pragma unroll
        for (int cc = 0; cc < 8; ++cc) { e[cc] = __expf(lrow[cc] - m); den += e[cc]; }
        float rd = __builtin_amdgcn_rcpf(den);
        #pragma unroll
        for (int cc = 0; cc < 8; ++cc) r_arr[p * PXS + cc * 8 + ii] = e[cc] * rd;
    }
    __syncthreads();

    // iter 1
    #pragma unroll
    for (int r = 0; r < 4; ++r) {
        const float4* rp = (const float4*)&r_arr[(px0 + r) * PXS + c * 8];
        float4 r0 = rp[0], r1 = rp[1];
        float s;
        s  = r0.x * acc[0][r]; s = fmaf(r0.y, acc[1][r], s);
        s  = fmaf(r0.z, acc[2][r], s); s = fmaf(r0.w, acc[3][r], s);
        s  = fmaf(r1.x, acc[4][r], s); s = fmaf(r1.y, acc[5][r], s);
        s  = fmaf(r1.z, acc[6][r], s); s = fmaf(r1.w, acc[7][r], s);
        float pre = s + bb;
        float s2 = sum16(pre * pre);
        float scale = s2 * __builtin_amdgcn_rsqf(s2 + EPS) * __builtin_amdgcn_rcpf(1.f + s2);
        act[r] = scale * pre;
    }
    #pragma unroll
    for (int i = 0; i < 8; ++i)
        #pragma unroll
        for (int r = 0; r < 4; ++r) {
            float a = sum16(acc[i][r] * act[r]);
            if (fi == 0) lg_arr[(px0 + r) * LSTRIDE + i * 9 + c] += a;
        }
    __syncthreads();
    if (tid < 256) {
        int p = tid >> 3, ii = tid & 7;
        const float* lrow = &lg_arr[p * LSTRIDE + ii * 9];
        float m = lrow[0];
        #pragma unroll
        for (int cc = 1; cc < 8; ++cc) m = fmaxf(m, lrow[cc]);
        float e[8]; float den = 0.f;
        #pragma unroll
        for (int cc = 0; cc < 8; ++cc) { e[cc] = __expf(lrow[cc] - m); den += e[cc]; }
        float rd = __builtin_amdgcn_rcpf(den);
        #pragma unroll
        for (int cc = 0; cc < 8; ++cc) r_arr[p * PXS + cc * 8 + ii] = e[cc] * rd;
    }
    __syncthreads();

    // iter 2: final activation -> out
    #pragma unroll
    for (int r = 0; r < 4; ++r) {
        const float4* rp = (const float4*)&r_arr[(px0 + r) * PXS + c * 8];
        float4 r0 = rp[0], r1 = rp[1];
        float s;
        s  = r0.x * acc[0][r]; s = fmaf(r0.y, acc[1][r], s);
        s  = fmaf(r0.z, acc[2][r], s); s = fmaf(r0.w, acc[3][r], s);
        s  = fmaf(r1.x, acc[4][r], s); s = fmaf(r1.y, acc[5][r], s);
        s  = fmaf(r1.z, acc[6][r], s); s = fmaf(r1.w, acc[7][r], s);
        float pre = s + bb;
        float s2 = sum16(pre * pre);
        float scale = s2 * __builtin_amdgcn_rsqf(s2 + EPS) * __builtin_amdgcn_rcpf(1.f + s2);
        int px = px0 + r;
        out[(((b * 32 + h) * 32 + px) << 7) + c * 16 + fi] = scale * pre;
    }
}

extern "C" void kernel_launch(void* const* d_in, const int* in_sizes, int n_in,
                              void* d_out, int out_size, void* d_ws, size_t ws_size,
                              hipStream_t stream) {
    const float* x    = (const float*)d_in[0];
    const float* wts  = (const float*)d_in[1];
    const float* bias = (const float*)d_in[2];
    float* out        = (float*)d_out;
    _Float16* w16     = (_Float16*)d_ws;

    prep_weights<<<dim3(640), dim3(256), 0, stream>>>(wts, w16);
    capsule_mfma_kernel<<<dim3(1024), dim3(1024), 0, stream>>>(x, w16, bias, out);
}